// Round 6
// baseline (317.057 us; speedup 1.0000x reference)
//
#include <hip/hip_runtime.h>

#define LOG2E      1.44269504088896340736f
#define TWO_LOG2E  2.88539008177792680472f

typedef float f2 __attribute__((ext_vector_type(2)));

__device__ __forceinline__ float frcp(float x)  { return __builtin_amdgcn_rcpf(x); }
__device__ __forceinline__ float fexp2(float x) { return __builtin_amdgcn_exp2f(x); }

__device__ __forceinline__ f2 pk_mul(f2 a, f2 b) {
    f2 d; asm("v_pk_mul_f32 %0, %1, %2" : "=v"(d) : "v"(a), "v"(b)); return d;
}
__device__ __forceinline__ f2 pk_fma(f2 a, f2 b, f2 c) {
    f2 d; asm("v_pk_fma_f32 %0, %1, %2, %3" : "=v"(d) : "v"(a), "v"(b), "v"(c)); return d;
}
__device__ __forceinline__ f2 pk_add(f2 a, f2 b) {
    f2 d; asm("v_pk_add_f32 %0, %1, %2" : "=v"(d) : "v"(a), "v"(b)); return d;
}
__device__ __forceinline__ f2 f2lo(float4 v) { f2 r; r.x = v.x; r.y = v.y; return r; }
__device__ __forceinline__ f2 f2hi(float4 v) { f2 r; r.x = v.z; r.y = v.w; return r; }

// async global->LDS, 16B per lane. LDS dest = wave-uniform base + lane*16.
__device__ __forceinline__ void gload_lds16(const float* g, float* l) {
    auto gp = (const __attribute__((address_space(1))) float*)g;
    auto lp = (__attribute__((address_space(3))) float*)l;
    __builtin_amdgcn_global_load_lds(gp, lp, 16, 0, 0);
}

// Layout (all fp32):
//   images [32,1024,64,16] -> off(n,b,s,d) = n*1048576 + b*1024 + s*16 + d
//   out    [32,1024,64,16] -> same
// One wave = one chain b. ROW-MAJOR lane map: row a = lane>>4 (a gate, mapping
// probed at runtime), pos j = lane&15 (hidden unit). Weight row = gate*16+j.
// Recurrent dot = 16 DPP row_ror fmacs on hv. Gates gathered via
// permlane16/32_swap. Weights/bias pre-scaled by each activation's exp2
// coefficient; tanh gate folds K=2log2e so c' = K*c is tracked.
// x pipeline: SINGLE 64-VGPR buffer. Phase P+1's 16 ds_read_b128 are issued
// (pinned volatile asm) before phase P's 4 STEPs (~300 cyc cover), waited
// with one lgkmcnt(0) before PROJ. Chunks staged to LDS by global_load_lds
// two chunks (~16 phases) early, drained by one vmcnt(0) mid-chunk.

__global__ __launch_bounds__(256, 1)
void lstm_fused(const float* __restrict__ images,
                const float* __restrict__ w_ih,
                const float* __restrict__ w_hh,
                const float* __restrict__ b_ih,
                const float* __restrict__ b_hh,
                float* __restrict__ out)
{
    __shared__ float4 xlds[4][2][256];   // [wave][buf][1 KB as float4] = 32 KB

    const int lane = threadIdx.x & 63;
    const int wid  = threadIdx.x >> 6;
    const int b    = (blockIdx.x << 2) + wid;   // 0..1023
    const int a    = lane >> 4;                 // row 0..3
    const int j    = lane & 15;                 // unit 0..15

    // ---- runtime convention probes (init-only; verified passing R4/R5) ----
    int rr1 = __builtin_amdgcn_update_dpp(0, j, 0x121, 0xF, 0xF, true);
    const int d_ror = (rr1 - j) & 15;           // src pos of ror:t = (j + d_ror*t)&15

    int e16;
    { int pa = a, pb = a;
      asm volatile("s_nop 1\n\t"
                   "v_permlane16_swap_b32 %0, %1" : "+v"(pa), "+v"(pb));
      e16 = pa & 1; }
    int e32;
    { int pc = a, pd = a;
      asm volatile("s_nop 1\n\t"
                   "v_permlane32_swap_b32 %0, %1" : "+v"(pc), "+v"(pd));
      e32 = (pc < 2) ? 0 : 1; }

    const int m1 = ((a >> 1) == e32);
    const int m0 = ((a & 1) == e16);
    const int gate = m0 ? (m1 ? 1 : 2) : (m1 ? 0 : 3);  // torch: i=0,f=1,g=2,o=3
    const int r = gate * 16 + j;

    const float aa = (gate == 2) ? TWO_LOG2E : -LOG2E;
    const float mm = (gate == 2) ? -2.0f * TWO_LOG2E : 1.0f;
    const float dd = (gate == 2) ? TWO_LOG2E : 0.0f;

    float whh[16];
#pragma unroll
    for (int t = 0; t < 16; ++t)
        whh[t] = aa * w_hh[r * 16 + ((j + d_ror * t) & 15)];
    f2 wihp[8];
#pragma unroll
    for (int m = 0; m < 8; ++m) {
        f2 w; w.x = aa * w_ih[r * 16 + 2 * m]; w.y = aa * w_ih[r * 16 + 2 * m + 1];
        wihp[m] = w;
    }
    const float bias = aa * (b_ih[r] + b_hh[r]);

    // hoisted store-select masks (one v_cmp each, off the serial path)
    const bool su0 = (a == 0), su1 = (a == 1), su2 = (a == 2), su3 = (a == 3);

    float hv = 0.0f;   // h[j], replicated across rows
    float c  = 0.0f;   // K * c_true
    float sv = 0.0f;   // per-phase store value (row a holds step a)

    const int bbase = b << 10;  // b*1024

#define PB(p) ((((p) >> 4) << 20) + bbase + (((((p) << 2)) & 63) << 4))

#define GLOAD_CHUNK(n) {                                                       \
        const float* gp_ = images + ((n) << 20) + bbase + (lane << 2);         \
        float4* lb_ = &xlds[wid][(n) & 1][0];                                  \
        gload_lds16(gp_ + 0,   (float*)(lb_ + 0));                             \
        gload_lds16(gp_ + 256, (float*)(lb_ + 64));                            \
        gload_lds16(gp_ + 512, (float*)(lb_ + 128));                           \
        gload_lds16(gp_ + 768, (float*)(lb_ + 192)); }

    // PINNED issue of phase Q's 16 uniform ds_read_b128 into xv (volatile).
#define DSREADV(xv, Qraw) {                                                    \
        int Q_ = (Qraw); if (Q_ > 511) Q_ = 511;                               \
        auto lp_ = (const __attribute__((address_space(3))) float4*)           \
                   &xlds[wid][(Q_ >> 4) & 1][(Q_ & 15) << 4];                  \
        _Pragma("unroll")                                                      \
        for (int q = 0; q < 16; ++q)                                           \
            asm volatile("ds_read_b128 %0, %1 offset:%2"                       \
                : "=v"(xv[q]) : "v"(lp_), "i"(q * 16) : "memory");             \
    }

#define WAIT_LGKM() { asm volatile("s_waitcnt lgkmcnt(0)" ::: "memory");       \
                      __builtin_amdgcn_sched_barrier(0); }

    // xpre[u] = scaled bias + dot(scaled w_ih, x_t), packed-fp32
#define PROJ(xpre, xv) {                                                       \
        _Pragma("unroll")                                                      \
        for (int u = 0; u < 4; ++u) {                                          \
            f2 A_ = pk_mul(wihp[0], f2lo(xv[4*u+0]));                          \
            f2 B_ = pk_mul(wihp[1], f2hi(xv[4*u+0]));                          \
            A_ = pk_fma(wihp[2], f2lo(xv[4*u+1]), A_);                         \
            B_ = pk_fma(wihp[3], f2hi(xv[4*u+1]), B_);                         \
            A_ = pk_fma(wihp[4], f2lo(xv[4*u+2]), A_);                         \
            B_ = pk_fma(wihp[5], f2hi(xv[4*u+2]), B_);                         \
            A_ = pk_fma(wihp[6], f2lo(xv[4*u+3]), A_);                         \
            B_ = pk_fma(wihp[7], f2hi(xv[4*u+3]), B_);                         \
            A_ = pk_add(A_, B_);                                               \
            xpre[u] = (bias + A_.x) + A_.y;                                    \
        } }

    // one recurrence step; dot + gather asm are NON-volatile (pure dataflow)
    // so LLVM can interleave DSREAD issue / PROJ / STORE into stall slots.
#define STEP(SU, xpv) {                                                        \
        float p0 = (xpv), p1, p2, p3;                                          \
        asm("s_nop 1\n\t"                                                      \
          "v_fmac_f32 %[q0], %[h], %[w0]\n\t"                                  \
          "v_mul_f32 %[q1], %[h], %[w1] row_ror:1 row_mask:0xf bank_mask:0xf\n\t" \
          "v_mul_f32 %[q2], %[h], %[w2] row_ror:2 row_mask:0xf bank_mask:0xf\n\t" \
          "v_mul_f32 %[q3], %[h], %[w3] row_ror:3 row_mask:0xf bank_mask:0xf\n\t" \
          "v_fmac_f32 %[q0], %[h], %[w4] row_ror:4 row_mask:0xf bank_mask:0xf\n\t" \
          "v_fmac_f32 %[q1], %[h], %[w5] row_ror:5 row_mask:0xf bank_mask:0xf\n\t" \
          "v_fmac_f32 %[q2], %[h], %[w6] row_ror:6 row_mask:0xf bank_mask:0xf\n\t" \
          "v_fmac_f32 %[q3], %[h], %[w7] row_ror:7 row_mask:0xf bank_mask:0xf\n\t" \
          "v_fmac_f32 %[q0], %[h], %[w8] row_ror:8 row_mask:0xf bank_mask:0xf\n\t" \
          "v_fmac_f32 %[q1], %[h], %[w9] row_ror:9 row_mask:0xf bank_mask:0xf\n\t" \
          "v_fmac_f32 %[q2], %[h], %[w10] row_ror:10 row_mask:0xf bank_mask:0xf\n\t" \
          "v_fmac_f32 %[q3], %[h], %[w11] row_ror:11 row_mask:0xf bank_mask:0xf\n\t" \
          "v_fmac_f32 %[q0], %[h], %[w12] row_ror:12 row_mask:0xf bank_mask:0xf\n\t" \
          "v_fmac_f32 %[q1], %[h], %[w13] row_ror:13 row_mask:0xf bank_mask:0xf\n\t" \
          "v_fmac_f32 %[q2], %[h], %[w14] row_ror:14 row_mask:0xf bank_mask:0xf\n\t" \
          "v_fmac_f32 %[q3], %[h], %[w15] row_ror:15 row_mask:0xf bank_mask:0xf"   \
          : [q0]"+v"(p0), [q1]"=&v"(p1), [q2]"=&v"(p2), [q3]"=&v"(p3)          \
          : [h]"v"(hv),                                                        \
            [w0]"v"(whh[0]),  [w1]"v"(whh[1]),  [w2]"v"(whh[2]),  [w3]"v"(whh[3]), \
            [w4]"v"(whh[4]),  [w5]"v"(whh[5]),  [w6]"v"(whh[6]),  [w7]"v"(whh[7]), \
            [w8]"v"(whh[8]),  [w9]"v"(whh[9]),  [w10]"v"(whh[10]),[w11]"v"(whh[11]),\
            [w12]"v"(whh[12]),[w13]"v"(whh[13]),[w14]"v"(whh[14]),[w15]"v"(whh[15]));\
        float arg = (p0 + p1) + (p2 + p3);                                     \
        float act = fmaf(mm, frcp(1.0f + fexp2(arg)), dd);                     \
        float qf, qg, qi, qo;                                                  \
        asm("v_mov_b32 %[A], %[x]\n\t"                                         \
          "v_mov_b32 %[B], %[x]\n\t"                                           \
          "s_nop 1\n\t"                                                        \
          "v_permlane16_swap_b32 %[A], %[B]\n\t"                               \
          "v_mov_b32 %[C], %[A]\n\t"                                           \
          "v_mov_b32 %[D], %[B]\n\t"                                           \
          "v_permlane32_swap_b32 %[A], %[C]\n\t"                               \
          "v_permlane32_swap_b32 %[B], %[D]"                                   \
          : [A]"=&v"(qf), [B]"=&v"(qi), [C]"=&v"(qg), [D]"=&v"(qo)             \
          : [x]"v"(act));                                                      \
        float ig = qi * qg;                                                    \
        float qo2 = qo + qo;                                                   \
        c = fmaf(c, qf, ig);                                                   \
        float rr = frcp(1.0f + fexp2(c));                                      \
        hv = fmaf(-qo2, rr, qo);                                               \
        sv = (SU) ? hv : sv;                                                   \
    }

#define STORE(pb) out[(pb) + lane] = sv;

    float4 xv[16];
    float  xpre[4];

    // prologue: stage chunks 0,1; prime phase 0
    GLOAD_CHUNK(0);
    GLOAD_CHUNK(1);
    asm volatile("s_waitcnt vmcnt(0)" ::: "memory");
    DSREADV(xv, 0);
    WAIT_LGKM();
    PROJ(xpre, xv);

#pragma unroll 1
    for (int P = 0; P < 512; ++P) {
        DSREADV(xv, P + 1);                // pinned early issue (phase P+1)
        {
            const int pb = PB(P);
            STEP(su0, xpre[0]);
            STEP(su1, xpre[1]);
            STEP(su2, xpre[2]);
            STEP(su3, xpre[3]);
            STORE(pb);
        }
        if ((P & 15) == 8)                 // chunk staging guaranteed done
            asm volatile("s_waitcnt vmcnt(0)" ::: "memory");
        WAIT_LGKM();                       // drain this iter's 16 ds_reads
        PROJ(xpre, xv);                    // phase P+1
        if ((P & 15) == 14 && P < 480)
            GLOAD_CHUNK((P >> 4) + 2);     // stage chunk+2, ~16 phases early
    }

#undef STEP
#undef STORE
#undef PROJ
#undef WAIT_LGKM
#undef DSREADV
#undef GLOAD_CHUNK
#undef PB
}

extern "C" void kernel_launch(void* const* d_in, const int* in_sizes, int n_in,
                              void* d_out, int out_size, void* d_ws, size_t ws_size,
                              hipStream_t stream)
{
    const float* images = (const float*)d_in[0];
    const float* w_ih   = (const float*)d_in[1];
    const float* w_hh   = (const float*)d_in[2];
    const float* b_ih   = (const float*)d_in[3];
    const float* b_hh   = (const float*)d_in[4];
    float* outp         = (float*)d_out;

    lstm_fused<<<dim3(256), dim3(256), 0, stream>>>(images, w_ih, w_hh, b_ih, b_hh, outp);
}

// Round 7
// 311.323 us; speedup vs baseline: 1.0184x; 1.0184x over previous
//
#include <hip/hip_runtime.h>

#define LOG2E      1.44269504088896340736f
#define TWO_LOG2E  2.88539008177792680472f

typedef float f16v __attribute__((ext_vector_type(16)));

__device__ __forceinline__ float frcp(float x)  { return __builtin_amdgcn_rcpf(x); }
__device__ __forceinline__ float fexp2(float x) { return __builtin_amdgcn_exp2f(x); }

// Layout (all fp32):
//   images [32,1024,64,16] -> off(n,b,s,d) = n*1048576 + b*1024 + s*16 + d
//   out    [32,1024,64,16] -> same
// One wave = one chain b. ROW-MAJOR lane map: row a = lane>>4 (a gate, mapping
// probed at runtime), pos j = lane&15 (hidden unit). Weight row = gate*16+j.
// Recurrent dot = 16 DPP row_ror fmacs on hv. Gates gathered via
// permlane16/32_swap. Weights/bias pre-scaled by each activation's exp2
// coefficient; tanh gate folds K=2log2e so c' = K*c is tracked.
// x pipeline: x is WAVE-UNIFORM -> loaded via 4x s_load_dwordx16 into a
// 64-SGPR buffer (SMEM pipe, zero VALU issue, zero VGPR pressure), issued
// one phase (~550 cyc) ahead, drained by one lgkmcnt(0)+sched_barrier
// before PROJ. No LDS, no global_load_lds, no vector loads at all.

__global__ __launch_bounds__(256, 1)
void lstm_fused(const float* __restrict__ images,
                const float* __restrict__ w_ih,
                const float* __restrict__ w_hh,
                const float* __restrict__ b_ih,
                const float* __restrict__ b_hh,
                float* __restrict__ out)
{
    const int lane = threadIdx.x & 63;
    const int wid  = threadIdx.x >> 6;
    const int b    = (blockIdx.x << 2) + wid;   // 0..1023
    const int a    = lane >> 4;                 // row 0..3
    const int j    = lane & 15;                 // unit 0..15

    // ---- runtime convention probes (init-only; verified passing R4-R6) ----
    int rr1 = __builtin_amdgcn_update_dpp(0, j, 0x121, 0xF, 0xF, true);
    const int d_ror = (rr1 - j) & 15;           // src pos of ror:t = (j + d_ror*t)&15

    int e16;
    { int pa = a, pb = a;
      asm volatile("s_nop 1\n\t"
                   "v_permlane16_swap_b32 %0, %1" : "+v"(pa), "+v"(pb));
      e16 = pa & 1; }
    int e32;
    { int pc = a, pd = a;
      asm volatile("s_nop 1\n\t"
                   "v_permlane32_swap_b32 %0, %1" : "+v"(pc), "+v"(pd));
      e32 = (pc < 2) ? 0 : 1; }

    const int m1 = ((a >> 1) == e32);
    const int m0 = ((a & 1) == e16);
    const int gate = m0 ? (m1 ? 1 : 2) : (m1 ? 0 : 3);  // torch: i=0,f=1,g=2,o=3
    const int r = gate * 16 + j;

    const float aa = (gate == 2) ? TWO_LOG2E : -LOG2E;
    const float mm = (gate == 2) ? -2.0f * TWO_LOG2E : 1.0f;
    const float dd = (gate == 2) ? TWO_LOG2E : 0.0f;

    float whh[16];
#pragma unroll
    for (int t = 0; t < 16; ++t)
        whh[t] = aa * w_hh[r * 16 + ((j + d_ror * t) & 15)];
    float wih[16];
#pragma unroll
    for (int k = 0; k < 16; ++k)
        wih[k] = aa * w_ih[r * 16 + k];
    const float bias = aa * (b_ih[r] + b_hh[r]);

    // hoisted store-select masks (one v_cmp each, off the serial path)
    const bool su0 = (a == 0), su1 = (a == 1), su2 = (a == 2), su3 = (a == 3);

    float hv = 0.0f;   // h[j], replicated across rows
    float c  = 0.0f;   // K * c_true
    float sv = 0.0f;   // per-phase store value (row a holds step a)

    const int bbase = b << 10;                          // b*1024 (floats)
    const unsigned wb = __builtin_amdgcn_readfirstlane(b);
    const unsigned long long img_u = (unsigned long long)images;

    // phase P covers steps t = 4P..4P+3; output base float offset:
#define PB(p) ((((p) >> 4) << 20) + bbase + (((((p) << 2)) & 63) << 4))

    // byte address of phase p's 256B x-slice (wave-uniform, 64B-aligned)
#define SBASE(p) (img_u + (((unsigned long long)((p) >> 4)) << 22)             \
                        + (((unsigned long long)wb) << 12)                     \
                        + (unsigned long long)(((p) & 15) << 8))

    // issue 4 scalar x16 loads for one phase (SMEM pipe; volatile pins issue)
#define SLOADP(Qraw) {                                                         \
        int Q_ = (Qraw); if (Q_ > 511) Q_ = 511;                               \
        unsigned long long sb_ = SBASE(Q_);                                    \
        asm volatile("s_load_dwordx16 %0, %4, 0x0\n\t"                         \
                     "s_load_dwordx16 %1, %4, 0x40\n\t"                        \
                     "s_load_dwordx16 %2, %4, 0x80\n\t"                        \
                     "s_load_dwordx16 %3, %4, 0xc0"                            \
                     : "=s"(sx0), "=s"(sx1), "=s"(sx2), "=s"(sx3)              \
                     : "s"(sb_));                                              \
    }

#define WAIT_LGKM() { asm volatile("s_waitcnt lgkmcnt(0)" ::: "memory");       \
                      __builtin_amdgcn_sched_barrier(0); }

    // xpre[u] = scaled bias + dot(scaled w_ih, x_t); sx* are SGPR-resident,
    // so each fmaf is one v_fmac_f32 vdst, sK, vwih.
#define PROJ1(dst, sx) {                                                       \
        float s0_ = bias, s1_ = 0.f, s2_ = 0.f, s3_ = 0.f;                     \
        _Pragma("unroll")                                                      \
        for (int k_ = 0; k_ < 4; ++k_) {                                       \
            s0_ = fmaf(sx[4*k_+0], wih[4*k_+0], s0_);                          \
            s1_ = fmaf(sx[4*k_+1], wih[4*k_+1], s1_);                          \
            s2_ = fmaf(sx[4*k_+2], wih[4*k_+2], s2_);                          \
            s3_ = fmaf(sx[4*k_+3], wih[4*k_+3], s3_);                          \
        }                                                                      \
        dst = (s0_ + s1_) + (s2_ + s3_);                                       \
    }
#define PROJ4() { PROJ1(xpre[0], sx0); PROJ1(xpre[1], sx1);                    \
                  PROJ1(xpre[2], sx2); PROJ1(xpre[3], sx3); }

    // one recurrence step; dot + gather asm are NON-volatile (pure dataflow)
#define STEP(SU, xpv) {                                                        \
        float p0 = (xpv), p1, p2, p3;                                          \
        asm("s_nop 1\n\t"                                                      \
          "v_fmac_f32 %[q0], %[h], %[w0]\n\t"                                  \
          "v_mul_f32 %[q1], %[h], %[w1] row_ror:1 row_mask:0xf bank_mask:0xf\n\t" \
          "v_mul_f32 %[q2], %[h], %[w2] row_ror:2 row_mask:0xf bank_mask:0xf\n\t" \
          "v_mul_f32 %[q3], %[h], %[w3] row_ror:3 row_mask:0xf bank_mask:0xf\n\t" \
          "v_fmac_f32 %[q0], %[h], %[w4] row_ror:4 row_mask:0xf bank_mask:0xf\n\t" \
          "v_fmac_f32 %[q1], %[h], %[w5] row_ror:5 row_mask:0xf bank_mask:0xf\n\t" \
          "v_fmac_f32 %[q2], %[h], %[w6] row_ror:6 row_mask:0xf bank_mask:0xf\n\t" \
          "v_fmac_f32 %[q3], %[h], %[w7] row_ror:7 row_mask:0xf bank_mask:0xf\n\t" \
          "v_fmac_f32 %[q0], %[h], %[w8] row_ror:8 row_mask:0xf bank_mask:0xf\n\t" \
          "v_fmac_f32 %[q1], %[h], %[w9] row_ror:9 row_mask:0xf bank_mask:0xf\n\t" \
          "v_fmac_f32 %[q2], %[h], %[w10] row_ror:10 row_mask:0xf bank_mask:0xf\n\t" \
          "v_fmac_f32 %[q3], %[h], %[w11] row_ror:11 row_mask:0xf bank_mask:0xf\n\t" \
          "v_fmac_f32 %[q0], %[h], %[w12] row_ror:12 row_mask:0xf bank_mask:0xf\n\t" \
          "v_fmac_f32 %[q1], %[h], %[w13] row_ror:13 row_mask:0xf bank_mask:0xf\n\t" \
          "v_fmac_f32 %[q2], %[h], %[w14] row_ror:14 row_mask:0xf bank_mask:0xf\n\t" \
          "v_fmac_f32 %[q3], %[h], %[w15] row_ror:15 row_mask:0xf bank_mask:0xf"   \
          : [q0]"+v"(p0), [q1]"=&v"(p1), [q2]"=&v"(p2), [q3]"=&v"(p3)          \
          : [h]"v"(hv),                                                        \
            [w0]"v"(whh[0]),  [w1]"v"(whh[1]),  [w2]"v"(whh[2]),  [w3]"v"(whh[3]), \
            [w4]"v"(whh[4]),  [w5]"v"(whh[5]),  [w6]"v"(whh[6]),  [w7]"v"(whh[7]), \
            [w8]"v"(whh[8]),  [w9]"v"(whh[9]),  [w10]"v"(whh[10]),[w11]"v"(whh[11]),\
            [w12]"v"(whh[12]),[w13]"v"(whh[13]),[w14]"v"(whh[14]),[w15]"v"(whh[15]));\
        float arg = (p0 + p1) + (p2 + p3);                                     \
        float act = fmaf(mm, frcp(1.0f + fexp2(arg)), dd);                     \
        float qf, qg, qi, qo;                                                  \
        asm("v_mov_b32 %[A], %[x]\n\t"                                         \
          "v_mov_b32 %[B], %[x]\n\t"                                           \
          "s_nop 1\n\t"                                                        \
          "v_permlane16_swap_b32 %[A], %[B]\n\t"                               \
          "v_mov_b32 %[C], %[A]\n\t"                                           \
          "v_mov_b32 %[D], %[B]\n\t"                                           \
          "v_permlane32_swap_b32 %[A], %[C]\n\t"                               \
          "v_permlane32_swap_b32 %[B], %[D]"                                   \
          : [A]"=&v"(qf), [B]"=&v"(qi), [C]"=&v"(qg), [D]"=&v"(qo)             \
          : [x]"v"(act));                                                      \
        float ig = qi * qg;                                                    \
        float qo2 = qo + qo;                                                   \
        c = fmaf(c, qf, ig);                                                   \
        float rr = frcp(1.0f + fexp2(c));                                      \
        hv = fmaf(-qo2, rr, qo);                                               \
        sv = (SU) ? hv : sv;                                                   \
    }

#define STORE(pb) out[(pb) + lane] = sv;

    f16v  sx0, sx1, sx2, sx3;   // 64-SGPR x buffer (one phase)
    float xpre[4];

    // prologue: load phase 0, project it
    SLOADP(0);
    WAIT_LGKM();
    PROJ4();

#pragma unroll 1
    for (int P = 0; P < 512; ++P) {
        SLOADP(P + 1);                     // SMEM prefetch, ~550 cyc ahead
        {
            const int pb = PB(P);
            STEP(su0, xpre[0]);
            STEP(su1, xpre[1]);
            STEP(su2, xpre[2]);
            STEP(su3, xpre[3]);
            STORE(pb);
        }
        WAIT_LGKM();                       // drain this iter's 4 s_loads
        PROJ4();                           // phase P+1
    }

#undef STEP
#undef STORE
#undef PROJ4
#undef PROJ1
#undef WAIT_LGKM
#undef SLOADP
#undef SBASE
#undef PB
}

extern "C" void kernel_launch(void* const* d_in, const int* in_sizes, int n_in,
                              void* d_out, int out_size, void* d_ws, size_t ws_size,
                              hipStream_t stream)
{
    const float* images = (const float*)d_in[0];
    const float* w_ih   = (const float*)d_in[1];
    const float* w_hh   = (const float*)d_in[2];
    const float* b_ih   = (const float*)d_in[3];
    const float* b_hh   = (const float*)d_in[4];
    float* outp         = (float*)d_out;

    lstm_fused<<<dim3(256), dim3(256), 0, stream>>>(images, w_ih, w_hh, b_ih, b_hh, outp);
}